// Round 7
// baseline (1017.517 us; speedup 1.0000x reference)
//
#include <hip/hip_runtime.h>
#include <math.h>

#define NBOND 7
#define NLAY 8
#define NTYPE 6
#define NNODES 16384   // B*N = 128*128
#define PX 136         // LDS pitch in halves (272 B = 16B-aligned rows; proven round 5)

typedef _Float16 half8 __attribute__((ext_vector_type(8)));
typedef _Float16 half4 __attribute__((ext_vector_type(4)));
typedef float floatx16 __attribute__((ext_vector_type(16)));

__device__ __forceinline__ float sig_(float x) { return 1.0f / (1.0f + __expf(-x)); }
// D-layout for 32x32 MFMA: col = lane&31, row = (reg&3) + 8*(reg>>2) + 4*(lane>>5)
__device__ __forceinline__ int drow_(int reg, int hi) { return (reg & 3) + 8 * (reg >> 2) + 4 * hi; }

__device__ __forceinline__ _Float16 hi_(float v) { return (_Float16)v; }
__device__ __forceinline__ _Float16 lo_(float v) { return (_Float16)(v - (float)(_Float16)v); }

// ---------------------------------------------------------------- setup
__global__ void setup_kernel(const float* __restrict__ h, float* __restrict__ hT,
                             int* __restrict__ counts, int* __restrict__ bucket)
{
    int gid = blockIdx.x * 256 + threadIdx.x;
    int node = gid >> 7, d = gid & 127;
    hT[gid] = (d < 75) ? h[node * 75 + d] : 0.0f;
    if (gid < NNODES) {
        float a = h[gid * 75];
        int tt = 5;
        if      (a == 6.0f) tt = 0;
        else if (a == 7.0f) tt = 1;
        else if (a == 8.0f) tt = 2;
        else if (a == 9.0f) tt = 3;
        else if (a == 0.0f) tt = 4;
        int slot = atomicAdd(&counts[tt], 1);
        bucket[tt * NNODES + slot] = gid;
    }
}

// ---------------------------------------------------------------- weight packing (fp32 -> split fp16 hi/lo planes)
// msgW: [(kb*8+l)][c 0..15][plane hi/lo][e 0..127][j 0..7]  (j along input dim d)
// Serves BOTH as A-frag (lane = e, j = k) and B-frag (lane = e-col, j = k).
__global__ void pack_msg_kernel(const float* __restrict__ msgW, _Float16* __restrict__ Wp)
{
    int idx = blockIdx.x * 256 + threadIdx.x;
    if (idx >= NBOND * NLAY * 16 * 128) return;
    int e  = idx & 127;
    int c  = (idx >> 7) & 15;
    int kl = idx >> 11;
    const float* src = msgW + ((size_t)kl * 128 + e) * 128 + c * 8;
    float4 u = *(const float4*)src;
    float4 v = *(const float4*)(src + 4);
    float av[8] = {u.x, u.y, u.z, u.w, v.x, v.y, v.z, v.w};
    half8 hh, ll;
    #pragma unroll
    for (int j = 0; j < 8; ++j) { hh[j] = hi_(av[j]); ll[j] = lo_(av[j]); }
    _Float16* dst = Wp + ((size_t)kl * 16 + c) * 2048;
    *(half8*)(dst + e * 8)        = hh;
    *(half8*)(dst + 1024 + e * 8) = ll;
}

// GRU: [(vt*2+mat)][c 0..15][plane hi/lo][col 0..383][j 0..7]
__global__ void pack_gru_kernel(const float* __restrict__ Wih, const float* __restrict__ Whh,
                                _Float16* __restrict__ Wp)
{
    int idx = blockIdx.x * 256 + threadIdx.x;
    if (idx >= 2 * NTYPE * 2 * 16 * 384) return;
    int col = idx % 384;
    int c   = (idx / 384) & 15;
    int vm  = idx / 6144;       // (vt*2 + mat), vt = v*6+tt
    int mat = vm & 1;
    int vt  = vm >> 1;
    const float* src = (mat ? Whh : Wih) + ((size_t)vt * 384 + col) * 128 + c * 8;
    float4 u = *(const float4*)src;
    float4 v = *(const float4*)(src + 4);
    float av[8] = {u.x, u.y, u.z, u.w, v.x, v.y, v.z, v.w};
    half8 hh, ll;
    #pragma unroll
    for (int j = 0; j < 8; ++j) { hh[j] = hi_(av[j]); ll[j] = lo_(av[j]); }
    _Float16* dst = Wp + (size_t)vm * 98304 + (size_t)c * 6144;
    *(half8*)(dst + col * 8)        = hh;
    *(half8*)(dst + 3072 + col * 8) = ll;
}

// ---------------------------------------------------------------- MLP + aggregation (split-fp16 MFMA)
// One block per (kb, b). Layers 0-6 as out^T = W·X^T: A = W (L2), B = X (LDS),
// D col = node -> wide half4 write-back of own row. FULL barrier discipline
// (2 per layer, round-5 proven): round 6's barrier-free variant raced.
__global__ __launch_bounds__(256) void mlp_agg_mfma(
    const float* __restrict__ hT, const _Float16* __restrict__ Wp,
    const float* __restrict__ gmat, float* __restrict__ m_non, float* __restrict__ m_uni)
{
    __shared__ _Float16 Xhi[128 * PX];
    __shared__ _Float16 Xlo[128 * PX];

    const int t = threadIdx.x;
    const int kb = blockIdx.x, b = blockIdx.y;
    const int wave = t >> 6, lane = t & 63, lo = lane & 31, hi = lane >> 5;
    const int node = wave * 32 + lo;

    // stage layer-0 activations (fp32 -> hi/lo fp16)
    for (int q = t; q < 128 * 32; q += 256) {
        int r = q >> 5, c4 = q & 31;
        float4 v = *(const float4*)(hT + ((size_t)(b * 128 + r)) * 128 + c4 * 4);
        half4 hh, ll;
        hh[0] = hi_(v.x); ll[0] = lo_(v.x);
        hh[1] = hi_(v.y); ll[1] = lo_(v.y);
        hh[2] = hi_(v.z); ll[2] = lo_(v.z);
        hh[3] = hi_(v.w); ll[3] = lo_(v.w);
        *(half4*)(Xhi + r * PX + c4 * 4) = hh;
        *(half4*)(Xlo + r * PX + c4 * 4) = ll;
    }
    __syncthreads();

    floatx16 acc[4];

    // ---- layers 0..6: out^T = W·X^T ----
    #pragma unroll 1
    for (int l = 0; l < NLAY - 1; ++l) {
        #pragma unroll
        for (int et = 0; et < 4; ++et) acc[et] = (floatx16)0.0f;
        const _Float16* wb = Wp + ((size_t)(kb * NLAY + l) * 16) * 2048;

        #pragma unroll 2
        for (int kk = 0; kk < 8; ++kk) {
            half8 x_h = *(const half8*)(Xhi + node * PX + kk * 16 + hi * 8);
            half8 x_l = *(const half8*)(Xlo + node * PX + kk * 16 + hi * 8);
            const _Float16* ap = wb + (size_t)(kk * 2 + hi) * 2048;
            #pragma unroll
            for (int et = 0; et < 4; ++et) {
                half8 w_h = *(const half8*)(ap + (et * 32 + lo) * 8);
                half8 w_l = *(const half8*)(ap + 1024 + (et * 32 + lo) * 8);
                acc[et] = __builtin_amdgcn_mfma_f32_32x32x16_f16(w_h, x_h, acc[et], 0, 0, 0);
                acc[et] = __builtin_amdgcn_mfma_f32_32x32x16_f16(w_h, x_l, acc[et], 0, 0, 0);
                acc[et] = __builtin_amdgcn_mfma_f32_32x32x16_f16(w_l, x_h, acc[et], 0, 0, 0);
            }
        }
        __syncthreads();   // all reads of X done
        // write-back: lane owns row `node`; e in 4-consecutive groups -> half4
        #pragma unroll
        for (int et = 0; et < 4; ++et)
            #pragma unroll
            for (int s = 0; s < 4; ++s) {
                int e0 = et * 32 + 8 * s + 4 * hi;
                half4 hh, ll;
                #pragma unroll
                for (int j = 0; j < 4; ++j) {
                    float vv = fmaxf(acc[et][4 * s + j], 0.0f);
                    hh[j] = hi_(vv); ll[j] = lo_(vv);
                }
                *(half4*)(Xhi + node * PX + e0) = hh;
                *(half4*)(Xlo + node * PX + e0) = ll;
            }
        __syncthreads();   // writes visible
    }

    // ---- layer 7: out = X·W, store transposed Xt[e][m] for agg ----
    #pragma unroll
    for (int et = 0; et < 4; ++et) acc[et] = (floatx16)0.0f;
    {
        const _Float16* wb = Wp + ((size_t)(kb * NLAY + (NLAY - 1)) * 16) * 2048;
        #pragma unroll 2
        for (int kk = 0; kk < 8; ++kk) {
            half8 x_h = *(const half8*)(Xhi + node * PX + kk * 16 + hi * 8);
            half8 x_l = *(const half8*)(Xlo + node * PX + kk * 16 + hi * 8);
            const _Float16* bp = wb + (size_t)(kk * 2 + hi) * 2048;
            #pragma unroll
            for (int et = 0; et < 4; ++et) {
                half8 w_h = *(const half8*)(bp + (et * 32 + lo) * 8);
                half8 w_l = *(const half8*)(bp + 1024 + (et * 32 + lo) * 8);
                acc[et] = __builtin_amdgcn_mfma_f32_32x32x16_f16(x_h, w_h, acc[et], 0, 0, 0);
                acc[et] = __builtin_amdgcn_mfma_f32_32x32x16_f16(x_h, w_l, acc[et], 0, 0, 0);
                acc[et] = __builtin_amdgcn_mfma_f32_32x32x16_f16(x_l, w_h, acc[et], 0, 0, 0);
            }
        }
    }
    __syncthreads();   // all waves done reading X
    #pragma unroll
    for (int et = 0; et < 4; ++et)
        #pragma unroll
        for (int s = 0; s < 4; ++s) {
            int e = et * 32 + lo, m0 = wave * 32 + 8 * s + 4 * hi;
            half4 hh, ll;
            #pragma unroll
            for (int j = 0; j < 4; ++j) {
                float vv = acc[et][4 * s + j];
                hh[j] = hi_(vv); ll[j] = lo_(vv);
            }
            *(half4*)(Xhi + e * PX + m0) = hh;
            *(half4*)(Xlo + e * PX + m0) = ll;
        }
    __syncthreads();

    // ---- aggregation: m[n][d] = sum_m g[b,kb,n,m]*xb[m][d];  A = g (inline split), B = Xt ----
    #pragma unroll
    for (int et = 0; et < 4; ++et) acc[et] = (floatx16)0.0f;
    const float* grow = gmat + (size_t)(b * NBOND + kb) * 16384;

    #pragma unroll 2
    for (int kk = 0; kk < 8; ++kk) {
        const float* gp = grow + (size_t)node * 128 + kk * 16 + hi * 8;
        float4 u = *(const float4*)gp, v2 = *(const float4*)(gp + 4);
        float av[8] = {u.x, u.y, u.z, u.w, v2.x, v2.y, v2.z, v2.w};
        half8 a_h, a_l;
        #pragma unroll
        for (int j = 0; j < 8; ++j) { a_h[j] = hi_(av[j]); a_l[j] = lo_(av[j]); }
        #pragma unroll
        for (int ct = 0; ct < 4; ++ct) {
            half8 b_h = *(const half8*)(Xhi + (ct * 32 + lo) * PX + kk * 16 + hi * 8);
            half8 b_l = *(const half8*)(Xlo + (ct * 32 + lo) * PX + kk * 16 + hi * 8);
            acc[ct] = __builtin_amdgcn_mfma_f32_32x32x16_f16(a_h, b_h, acc[ct], 0, 0, 0);
            acc[ct] = __builtin_amdgcn_mfma_f32_32x32x16_f16(a_h, b_l, acc[ct], 0, 0, 0);
            acc[ct] = __builtin_amdgcn_mfma_f32_32x32x16_f16(a_l, b_h, acc[ct], 0, 0, 0);
        }
    }

    if (kb == NBOND - 1) {
        #pragma unroll
        for (int ct = 0; ct < 4; ++ct)
            #pragma unroll
            for (int reg = 0; reg < 16; ++reg) {
                int n = wave * 32 + drow_(reg, hi);
                m_uni[((size_t)(b * 128 + n)) * 128 + ct * 32 + lo] = acc[ct][reg];
            }
    } else {
        #pragma unroll
        for (int ct = 0; ct < 4; ++ct)
            #pragma unroll
            for (int reg = 0; reg < 16; ++reg) {
                int n = wave * 32 + drow_(reg, hi);
                atomicAdd(m_non + ((size_t)(b * 128 + n)) * 128 + ct * 32 + lo, acc[ct][reg]);
            }
    }
}

// ---------------------------------------------------------------- grouped GRU (split-fp16 MFMA)
// Block = 64 gathered nodes of one type; wave w owns d in [w*32, w*32+32).
// v outer (Ms staged once per v), rt fused in kk loop, gates in two passes.
__global__ __launch_bounds__(256) void gru_mfma(
    float* __restrict__ hT, const float* __restrict__ m_non, const float* __restrict__ m_uni,
    const int* __restrict__ counts, const int* __restrict__ bucket,
    const _Float16* __restrict__ Wp, const float* __restrict__ bihp, const float* __restrict__ bhhp)
{
    __shared__ _Float16 Xh[64 * PX], Xl[64 * PX], Mh[64 * PX], Ml[64 * PX];
    __shared__ int bl[64];

    const int t = threadIdx.x, tt = blockIdx.y;
    const int cnt  = counts[tt];
    const int base = blockIdx.x * 64;
    if (base >= cnt) return;
    const int nn = min(64, cnt - base);
    if (t < 64) bl[t] = (t < nn) ? bucket[tt * NNODES + base + t] : -1;
    __syncthreads();

    const int wave = t >> 6, lane = t & 63, lo = lane & 31, hi = lane >> 5;
    const int d = wave * 32 + lo;

    // stage X once (gathered h rows, split fp16, zero-fill inactive)
    for (int q = t; q < 64 * 32; q += 256) {
        int r = q >> 5, c4 = q & 31;
        float4 v = make_float4(0.f, 0.f, 0.f, 0.f);
        int node = bl[r];
        if (node >= 0) v = *(const float4*)(hT + (size_t)node * 128 + c4 * 4);
        half4 hh, ll;
        hh[0] = hi_(v.x); ll[0] = lo_(v.x);
        hh[1] = hi_(v.y); ll[1] = lo_(v.y);
        hh[2] = hi_(v.z); ll[2] = lo_(v.z);
        hh[3] = hi_(v.w); ll[3] = lo_(v.w);
        *(half4*)(Xh + r * PX + c4 * 4) = hh;
        *(half4*)(Xl + r * PX + c4 * 4) = ll;
    }

    float hacc[2][16];
    #pragma unroll
    for (int rt = 0; rt < 2; ++rt)
        #pragma unroll
        for (int reg = 0; reg < 16; ++reg) hacc[rt][reg] = 0.0f;

    #pragma unroll 1
    for (int v = 0; v < 2; ++v) {
        const float* msrc = v ? m_uni : m_non;
        __syncthreads();   // prev-variant Ms readers done (v=0: X stage commit)
        for (int q = t; q < 64 * 32; q += 256) {
            int r = q >> 5, c4 = q & 31;
            float4 mv = make_float4(0.f, 0.f, 0.f, 0.f);
            int node = bl[r];
            if (node >= 0) mv = *(const float4*)(msrc + (size_t)node * 128 + c4 * 4);
            half4 hh, ll;
            hh[0] = hi_(mv.x); ll[0] = lo_(mv.x);
            hh[1] = hi_(mv.y); ll[1] = lo_(mv.y);
            hh[2] = hi_(mv.z); ll[2] = lo_(mv.z);
            hh[3] = hi_(mv.w); ll[3] = lo_(mv.w);
            *(half4*)(Mh + r * PX + c4 * 4) = hh;
            *(half4*)(Ml + r * PX + c4 * 4) = ll;
        }
        __syncthreads();

        const int vt = v * NTYPE + tt;
        const _Float16* pih = Wp + (size_t)(vt * 2 + 0) * 98304;
        const _Float16* phh = Wp + (size_t)(vt * 2 + 1) * 98304;
        const float* bi = bihp + (size_t)vt * 384;
        const float* bh = bhhp + (size_t)vt * 384;

        // ---- pass 1: gates r and z ----
        floatx16 ar[2], az[2];
        ar[0] = (floatx16)0.0f; ar[1] = (floatx16)0.0f;
        az[0] = (floatx16)0.0f; az[1] = (floatx16)0.0f;

        #pragma unroll 1
        for (int kk = 0; kk < 8; ++kk) {
            int koff = kk * 16 + hi * 8;
            const _Float16* ci = pih + (size_t)(kk * 2 + hi) * 6144;
            const _Float16* ch = phh + (size_t)(kk * 2 + hi) * 6144;
            half8 birh = *(const half8*)(ci + (size_t)(0 + d) * 8);
            half8 birl = *(const half8*)(ci + 3072 + (size_t)(0 + d) * 8);
            half8 bhrh = *(const half8*)(ch + (size_t)(0 + d) * 8);
            half8 bhrl = *(const half8*)(ch + 3072 + (size_t)(0 + d) * 8);
            half8 bizh = *(const half8*)(ci + (size_t)(128 + d) * 8);
            half8 bizl = *(const half8*)(ci + 3072 + (size_t)(128 + d) * 8);
            half8 bhzh = *(const half8*)(ch + (size_t)(128 + d) * 8);
            half8 bhzl = *(const half8*)(ch + 3072 + (size_t)(128 + d) * 8);
            #pragma unroll
            for (int rt = 0; rt < 2; ++rt) {
                const int rw = rt * 32 + lo;
                half8 xh = *(const half8*)(Xh + rw * PX + koff);
                half8 xl = *(const half8*)(Xl + rw * PX + koff);
                half8 mh = *(const half8*)(Mh + rw * PX + koff);
                half8 ml = *(const half8*)(Ml + rw * PX + koff);
                ar[rt] = __builtin_amdgcn_mfma_f32_32x32x16_f16(xh, birh, ar[rt], 0, 0, 0);
                ar[rt] = __builtin_amdgcn_mfma_f32_32x32x16_f16(xh, birl, ar[rt], 0, 0, 0);
                ar[rt] = __builtin_amdgcn_mfma_f32_32x32x16_f16(xl, birh, ar[rt], 0, 0, 0);
                ar[rt] = __builtin_amdgcn_mfma_f32_32x32x16_f16(mh, bhrh, ar[rt], 0, 0, 0);
                ar[rt] = __builtin_amdgcn_mfma_f32_32x32x16_f16(mh, bhrl, ar[rt], 0, 0, 0);
                ar[rt] = __builtin_amdgcn_mfma_f32_32x32x16_f16(ml, bhrh, ar[rt], 0, 0, 0);
                az[rt] = __builtin_amdgcn_mfma_f32_32x32x16_f16(xh, bizh, az[rt], 0, 0, 0);
                az[rt] = __builtin_amdgcn_mfma_f32_32x32x16_f16(xh, bizl, az[rt], 0, 0, 0);
                az[rt] = __builtin_amdgcn_mfma_f32_32x32x16_f16(xl, bizh, az[rt], 0, 0, 0);
                az[rt] = __builtin_amdgcn_mfma_f32_32x32x16_f16(mh, bhzh, az[rt], 0, 0, 0);
                az[rt] = __builtin_amdgcn_mfma_f32_32x32x16_f16(mh, bhzl, az[rt], 0, 0, 0);
                az[rt] = __builtin_amdgcn_mfma_f32_32x32x16_f16(ml, bhzh, az[rt], 0, 0, 0);
            }
        }

        float rr[2][16], zz[2][16];
        {
            float b_r = bi[d] + bh[d];
            float b_z = bi[128 + d] + bh[128 + d];
            #pragma unroll
            for (int rt = 0; rt < 2; ++rt)
                #pragma unroll
                for (int reg = 0; reg < 16; ++reg) {
                    rr[rt][reg] = sig_(ar[rt][reg] + b_r);
                    zz[rt][reg] = sig_(az[rt][reg] + b_z);
                }
        }

        // ---- pass 2: gate n ----
        floatx16 ax[2], ah[2];
        ax[0] = (floatx16)0.0f; ax[1] = (floatx16)0.0f;
        ah[0] = (floatx16)0.0f; ah[1] = (floatx16)0.0f;

        #pragma unroll 1
        for (int kk = 0; kk < 8; ++kk) {
            int koff = kk * 16 + hi * 8;
            const _Float16* ci = pih + (size_t)(kk * 2 + hi) * 6144;
            const _Float16* ch = phh + (size_t)(kk * 2 + hi) * 6144;
            half8 binh = *(const half8*)(ci + (size_t)(256 + d) * 8);
            half8 binl = *(const half8*)(ci + 3072 + (size_t)(256 + d) * 8);
            half8 bhnh = *(const half8*)(ch + (size_t)(256 + d) * 8);
            half8 bhnl = *(const half8*)(ch + 3072 + (size_t)(256 + d) * 8);
            #pragma unroll
            for (int rt = 0; rt < 2; ++rt) {
                const int rw = rt * 32 + lo;
                half8 xh = *(const half8*)(Xh + rw * PX + koff);
                half8 xl = *(const half8*)(Xl + rw * PX + koff);
                half8 mh = *(const half8*)(Mh + rw * PX + koff);
                half8 ml = *(const half8*)(Ml + rw * PX + koff);
                ax[rt] = __builtin_amdgcn_mfma_f32_32x32x16_f16(xh, binh, ax[rt], 0, 0, 0);
                ax[rt] = __builtin_amdgcn_mfma_f32_32x32x16_f16(xh, binl, ax[rt], 0, 0, 0);
                ax[rt] = __builtin_amdgcn_mfma_f32_32x32x16_f16(xl, binh, ax[rt], 0, 0, 0);
                ah[rt] = __builtin_amdgcn_mfma_f32_32x32x16_f16(mh, bhnh, ah[rt], 0, 0, 0);
                ah[rt] = __builtin_amdgcn_mfma_f32_32x32x16_f16(mh, bhnl, ah[rt], 0, 0, 0);
                ah[rt] = __builtin_amdgcn_mfma_f32_32x32x16_f16(ml, bhnh, ah[rt], 0, 0, 0);
            }
        }

        // ---- combine ----
        {
            float b_in = bi[256 + d];
            float b_hn = bh[256 + d];
            #pragma unroll
            for (int rt = 0; rt < 2; ++rt)
                #pragma unroll
                for (int reg = 0; reg < 16; ++reg) {
                    int n = rt * 32 + drow_(reg, hi);
                    int node = bl[n];
                    float nv = tanhf(ax[rt][reg] + b_in + rr[rt][reg] * (ah[rt][reg] + b_hn));
                    float mv = (node >= 0) ? msrc[(size_t)node * 128 + d] : 0.0f;
                    hacc[rt][reg] += (1.0f - zz[rt][reg]) * nv + zz[rt][reg] * mv;
                }
        }
    }

    // scatter h_new (coalesced along d)
    #pragma unroll
    for (int rt = 0; rt < 2; ++rt)
        #pragma unroll
        for (int reg = 0; reg < 16; ++reg) {
            int n = rt * 32 + drow_(reg, hi);
            int node = bl[n];
            if (node >= 0) hT[(size_t)node * 128 + d] = hacc[rt][reg];
        }
}

// ---------------------------------------------------------------- launch
extern "C" void kernel_launch(void* const* d_in, const int* in_sizes, int n_in,
                              void* d_out, int out_size, void* d_ws, size_t ws_size,
                              hipStream_t stream) {
    const float* g    = (const float*)d_in[0];
    const float* h    = (const float*)d_in[1];
    const float* msgW = (const float*)d_in[2];
    const float* Wih  = (const float*)d_in[3];
    const float* Whh  = (const float*)d_in[4];
    const float* bih  = (const float*)d_in[5];
    const float* bhh  = (const float*)d_in[6];
    float* hT = (float*)d_out;

    char* ws = (char*)d_ws;
    float* m_non = (float*)ws;                                   // 8 MB
    float* m_uni = m_non + (size_t)NNODES * 128;                 // 8 MB
    int* counts  = (int*)(ws + 2 * (size_t)NNODES * 128 * 4);
    int* bucket  = counts + 8;                                   // [6][16384]
    _Float16* WpM = (_Float16*)(bucket + NTYPE * NNODES);        // 1,835,008 halves (3.67 MB)
    _Float16* WpG = WpM + (size_t)NBOND * NLAY * 16 * 2048;      // 2,359,296 halves (4.72 MB)

    (void)hipMemsetAsync(counts, 0, 8 * sizeof(int), stream);
    setup_kernel<<<NNODES * 128 / 256, 256, 0, stream>>>(h, hT, counts, bucket);
    pack_msg_kernel<<<(NBOND * NLAY * 16 * 128 + 255) / 256, 256, 0, stream>>>(msgW, WpM);
    pack_gru_kernel<<<(2 * NTYPE * 2 * 16 * 384 + 255) / 256, 256, 0, stream>>>(Wih, Whh, WpG);

    for (int pass = 0; pass < 3; ++pass) {
        (void)hipMemsetAsync(m_non, 0, (size_t)NNODES * 128 * 4, stream);
        mlp_agg_mfma<<<dim3(NBOND, 128), 256, 0, stream>>>(hT, WpM, g, m_non, m_uni);
        gru_mfma<<<dim3(NNODES / 64, NTYPE), 256, 0, stream>>>(hT, m_non, m_uni, counts, bucket,
                                                               WpG, bih, bhh);
    }
}

// Round 8
// 960.167 us; speedup vs baseline: 1.0597x; 1.0597x over previous
//
#include <hip/hip_runtime.h>
#include <math.h>

#define NBOND 7
#define NLAY 8
#define NTYPE 6
#define NNODES 16384   // B*N = 128*128
#define PX 136         // LDS pitch in halves (272 B = 16B-aligned rows; proven)
#define GRUBLK 264     // max compacted GRU blocks (<= 256 + 6 rounding)

typedef _Float16 half8 __attribute__((ext_vector_type(8)));
typedef _Float16 half4 __attribute__((ext_vector_type(4)));
typedef float floatx16 __attribute__((ext_vector_type(16)));

__device__ __forceinline__ float sig_(float x) { return 1.0f / (1.0f + __expf(-x)); }
// D-layout for 32x32 MFMA: col = lane&31, row = (reg&3) + 8*(reg>>2) + 4*(lane>>5)
__device__ __forceinline__ int drow_(int reg, int hi) { return (reg & 3) + 8 * (reg >> 2) + 4 * hi; }

__device__ __forceinline__ _Float16 hi_(float v) { return (_Float16)v; }
__device__ __forceinline__ _Float16 lo_(float v) { return (_Float16)(v - (float)(_Float16)v); }

// ---------------------------------------------------------------- setup
__global__ void setup_kernel(const float* __restrict__ h, float* __restrict__ hT,
                             int* __restrict__ counts, int* __restrict__ bucket)
{
    int gid = blockIdx.x * 256 + threadIdx.x;
    int node = gid >> 7, d = gid & 127;
    hT[gid] = (d < 75) ? h[node * 75 + d] : 0.0f;
    if (gid < NNODES) {
        float a = h[gid * 75];
        int tt = 5;
        if      (a == 6.0f) tt = 0;
        else if (a == 7.0f) tt = 1;
        else if (a == 8.0f) tt = 2;
        else if (a == 9.0f) tt = 3;
        else if (a == 0.0f) tt = 4;
        int slot = atomicAdd(&counts[tt], 1);
        bucket[tt * NNODES + slot] = gid;
    }
}

// build compacted GRU block descriptors: desc[i] = (tt<<20)|base, balanced grid
__global__ void desc_kernel(const int* __restrict__ counts, int* __restrict__ desc,
                            int* __restrict__ nblk)
{
    if (threadIdx.x == 0) {
        int off = 0;
        for (int tt = 0; tt < NTYPE; ++tt) {
            int nb = (counts[tt] + 63) >> 6;
            for (int j = 0; j < nb; ++j) desc[off + j] = (tt << 20) | (j * 64);
            off += nb;
        }
        nblk[0] = off;
    }
}

// ---------------------------------------------------------------- weight packing (fp32 -> split fp16 hi/lo planes)
// msgW: [(kb*8+l)][c 0..15][plane hi/lo][e 0..127][j 0..7]  (j along input dim d)
__global__ void pack_msg_kernel(const float* __restrict__ msgW, _Float16* __restrict__ Wp)
{
    int idx = blockIdx.x * 256 + threadIdx.x;
    if (idx >= NBOND * NLAY * 16 * 128) return;
    int e  = idx & 127;
    int c  = (idx >> 7) & 15;
    int kl = idx >> 11;
    const float* src = msgW + ((size_t)kl * 128 + e) * 128 + c * 8;
    float4 u = *(const float4*)src;
    float4 v = *(const float4*)(src + 4);
    float av[8] = {u.x, u.y, u.z, u.w, v.x, v.y, v.z, v.w};
    half8 hh, ll;
    #pragma unroll
    for (int j = 0; j < 8; ++j) { hh[j] = hi_(av[j]); ll[j] = lo_(av[j]); }
    _Float16* dst = Wp + ((size_t)kl * 16 + c) * 2048;
    *(half8*)(dst + e * 8)        = hh;
    *(half8*)(dst + 1024 + e * 8) = ll;
}

// GRU: [(vt*2+mat)][c 0..15][plane hi/lo][col 0..383][j 0..7]
__global__ void pack_gru_kernel(const float* __restrict__ Wih, const float* __restrict__ Whh,
                                _Float16* __restrict__ Wp)
{
    int idx = blockIdx.x * 256 + threadIdx.x;
    if (idx >= 2 * NTYPE * 2 * 16 * 384) return;
    int col = idx % 384;
    int c   = (idx / 384) & 15;
    int vm  = idx / 6144;       // (vt*2 + mat), vt = v*6+tt
    int mat = vm & 1;
    int vt  = vm >> 1;
    const float* src = (mat ? Whh : Wih) + ((size_t)vt * 384 + col) * 128 + c * 8;
    float4 u = *(const float4*)src;
    float4 v = *(const float4*)(src + 4);
    float av[8] = {u.x, u.y, u.z, u.w, v.x, v.y, v.z, v.w};
    half8 hh, ll;
    #pragma unroll
    for (int j = 0; j < 8; ++j) { hh[j] = hi_(av[j]); ll[j] = lo_(av[j]); }
    _Float16* dst = Wp + (size_t)vm * 98304 + (size_t)c * 6144;
    *(half8*)(dst + col * 8)        = hh;
    *(half8*)(dst + 3072 + col * 8) = ll;
}

__device__ __forceinline__ void loadw8(half8* w, const _Float16* bp, int lo)
{
    #pragma unroll
    for (int et = 0; et < 4; ++et) {
        w[et]     = *(const half8*)(bp + (et * 32 + lo) * 8);
        w[4 + et] = *(const half8*)(bp + 1024 + (et * 32 + lo) * 8);
    }
}

// ---------------------------------------------------------------- MLP + aggregation (split-fp16 MFMA)
// One block per (b, kb). Layers 0-6 as out^T = W·X^T with W prefetched one
// kk-step ahead in registers (covers L2 latency at 2 waves/SIMD). Full barrier
// discipline (2/layer). Layer 7 as X·W -> transposed Xt for agg.
__global__ __launch_bounds__(256) void mlp_agg_mfma(
    const float* __restrict__ hT, const _Float16* __restrict__ Wp,
    const float* __restrict__ gmat, float* __restrict__ m_non, float* __restrict__ m_uni)
{
    __shared__ _Float16 Xhi[128 * PX];
    __shared__ _Float16 Xlo[128 * PX];

    const int t = threadIdx.x;
    const int b = blockIdx.x, kb = blockIdx.y;   // b fastest -> same-kb blocks co-resident per XCD
    const int wave = t >> 6, lane = t & 63, lo = lane & 31, hi = lane >> 5;
    const int node = wave * 32 + lo;

    // stage layer-0 activations (fp32 -> hi/lo fp16)
    for (int q = t; q < 128 * 32; q += 256) {
        int r = q >> 5, c4 = q & 31;
        float4 v = *(const float4*)(hT + ((size_t)(b * 128 + r)) * 128 + c4 * 4);
        half4 hh, ll;
        hh[0] = hi_(v.x); ll[0] = lo_(v.x);
        hh[1] = hi_(v.y); ll[1] = lo_(v.y);
        hh[2] = hi_(v.z); ll[2] = lo_(v.z);
        hh[3] = hi_(v.w); ll[3] = lo_(v.w);
        *(half4*)(Xhi + r * PX + c4 * 4) = hh;
        *(half4*)(Xlo + r * PX + c4 * 4) = ll;
    }
    __syncthreads();

    const _Float16* wbase = Wp + (size_t)(kb * NLAY) * 16 * 2048;
    floatx16 acc[4];
    half8 wc[8], wn[8];
    loadw8(wc, wbase + (size_t)hi * 2048, lo);   // (l=0, kk=0)

    // ---- layers 0..6: out^T = W·X^T ----
    #pragma unroll 1
    for (int l = 0; l < NLAY - 1; ++l) {
        #pragma unroll
        for (int et = 0; et < 4; ++et) acc[et] = (floatx16)0.0f;

        #pragma unroll
        for (int kk = 0; kk < 8; ++kk) {
            int nl = (kk == 7) ? l + 1 : l;
            int nk = (kk == 7) ? 0 : kk + 1;
            loadw8(wn, wbase + ((size_t)nl * 16 + nk * 2 + hi) * 2048, lo);
            half8 x_h = *(const half8*)(Xhi + node * PX + kk * 16 + hi * 8);
            half8 x_l = *(const half8*)(Xlo + node * PX + kk * 16 + hi * 8);
            #pragma unroll
            for (int et = 0; et < 4; ++et) {
                acc[et] = __builtin_amdgcn_mfma_f32_32x32x16_f16(wc[et], x_h, acc[et], 0, 0, 0);
                acc[et] = __builtin_amdgcn_mfma_f32_32x32x16_f16(wc[et], x_l, acc[et], 0, 0, 0);
                acc[et] = __builtin_amdgcn_mfma_f32_32x32x16_f16(wc[4 + et], x_h, acc[et], 0, 0, 0);
            }
            #pragma unroll
            for (int j = 0; j < 8; ++j) wc[j] = wn[j];
        }
        __syncthreads();   // all reads of X done
        #pragma unroll
        for (int et = 0; et < 4; ++et)
            #pragma unroll
            for (int s = 0; s < 4; ++s) {
                int e0 = et * 32 + 8 * s + 4 * hi;
                half4 hh, ll;
                #pragma unroll
                for (int j = 0; j < 4; ++j) {
                    float vv = fmaxf(acc[et][4 * s + j], 0.0f);
                    hh[j] = hi_(vv); ll[j] = lo_(vv);
                }
                *(half4*)(Xhi + node * PX + e0) = hh;
                *(half4*)(Xlo + node * PX + e0) = ll;
            }
        __syncthreads();   // writes visible
    }

    // ---- layer 7: out = X·W (wc holds (7,0)), store transposed Xt[e][m] ----
    #pragma unroll
    for (int et = 0; et < 4; ++et) acc[et] = (floatx16)0.0f;
    #pragma unroll
    for (int kk = 0; kk < 8; ++kk) {
        int nk = (kk == 7) ? 7 : kk + 1;
        loadw8(wn, wbase + ((size_t)7 * 16 + nk * 2 + hi) * 2048, lo);
        half8 x_h = *(const half8*)(Xhi + node * PX + kk * 16 + hi * 8);
        half8 x_l = *(const half8*)(Xlo + node * PX + kk * 16 + hi * 8);
        #pragma unroll
        for (int et = 0; et < 4; ++et) {
            acc[et] = __builtin_amdgcn_mfma_f32_32x32x16_f16(x_h, wc[et], acc[et], 0, 0, 0);
            acc[et] = __builtin_amdgcn_mfma_f32_32x32x16_f16(x_h, wc[4 + et], acc[et], 0, 0, 0);
            acc[et] = __builtin_amdgcn_mfma_f32_32x32x16_f16(x_l, wc[et], acc[et], 0, 0, 0);
        }
        #pragma unroll
        for (int j = 0; j < 8; ++j) wc[j] = wn[j];
    }
    __syncthreads();   // all waves done reading X
    #pragma unroll
    for (int et = 0; et < 4; ++et)
        #pragma unroll
        for (int s = 0; s < 4; ++s) {
            int e = et * 32 + lo, m0 = wave * 32 + 8 * s + 4 * hi;
            half4 hh, ll;
            #pragma unroll
            for (int j = 0; j < 4; ++j) {
                float vv = acc[et][4 * s + j];
                hh[j] = hi_(vv); ll[j] = lo_(vv);
            }
            *(half4*)(Xhi + e * PX + m0) = hh;
            *(half4*)(Xlo + e * PX + m0) = ll;
        }
    __syncthreads();

    // ---- aggregation: m[n][d] = sum_m g[b,kb,n,m]*xb[m][d];  A = g (inline split), B = Xt ----
    #pragma unroll
    for (int et = 0; et < 4; ++et) acc[et] = (floatx16)0.0f;
    const float* grow = gmat + (size_t)(b * NBOND + kb) * 16384;

    #pragma unroll 2
    for (int kk = 0; kk < 8; ++kk) {
        const float* gp = grow + (size_t)node * 128 + kk * 16 + hi * 8;
        float4 u = *(const float4*)gp, v2 = *(const float4*)(gp + 4);
        float av[8] = {u.x, u.y, u.z, u.w, v2.x, v2.y, v2.z, v2.w};
        half8 a_h, a_l;
        #pragma unroll
        for (int j = 0; j < 8; ++j) { a_h[j] = hi_(av[j]); a_l[j] = lo_(av[j]); }
        #pragma unroll
        for (int ct = 0; ct < 4; ++ct) {
            half8 b_h = *(const half8*)(Xhi + (ct * 32 + lo) * PX + kk * 16 + hi * 8);
            half8 b_l = *(const half8*)(Xlo + (ct * 32 + lo) * PX + kk * 16 + hi * 8);
            acc[ct] = __builtin_amdgcn_mfma_f32_32x32x16_f16(a_h, b_h, acc[ct], 0, 0, 0);
            acc[ct] = __builtin_amdgcn_mfma_f32_32x32x16_f16(a_h, b_l, acc[ct], 0, 0, 0);
            acc[ct] = __builtin_amdgcn_mfma_f32_32x32x16_f16(a_l, b_h, acc[ct], 0, 0, 0);
        }
    }

    if (kb == NBOND - 1) {
        #pragma unroll
        for (int ct = 0; ct < 4; ++ct)
            #pragma unroll
            for (int reg = 0; reg < 16; ++reg) {
                int n = wave * 32 + drow_(reg, hi);
                m_uni[((size_t)(b * 128 + n)) * 128 + ct * 32 + lo] = acc[ct][reg];
            }
    } else {
        #pragma unroll
        for (int ct = 0; ct < 4; ++ct)
            #pragma unroll
            for (int reg = 0; reg < 16; ++reg) {
                int n = wave * 32 + drow_(reg, hi);
                atomicAdd(m_non + ((size_t)(b * 128 + n)) * 128 + ct * 32 + lo, acc[ct][reg]);
            }
    }
}

// ---------------------------------------------------------------- grouped GRU (split-fp16 MFMA)
// Compacted grid (desc), 512 threads = 8 waves: wave -> (rt = wave>>2, d-tile =
// wave&3). 2 waves/SIMD at 1 block/CU; kk loops unroll-2 for load pipelining.
__global__ __launch_bounds__(512, 2) void gru_mfma(
    float* __restrict__ hT, const float* __restrict__ m_non, const float* __restrict__ m_uni,
    const int* __restrict__ counts, const int* __restrict__ bucket,
    const int* __restrict__ desc, const int* __restrict__ nblk,
    const _Float16* __restrict__ Wp, const float* __restrict__ bihp, const float* __restrict__ bhhp)
{
    __shared__ _Float16 Xh[64 * PX], Xl[64 * PX], Mh[64 * PX], Ml[64 * PX];
    __shared__ int bl[64];

    if (blockIdx.x >= nblk[0]) return;
    const int dsc = desc[blockIdx.x];
    const int tt = dsc >> 20, base = dsc & 0xFFFFF;
    const int cnt = counts[tt];
    const int nn = min(64, cnt - base);

    const int t = threadIdx.x;
    if (t < 64) bl[t] = (t < nn) ? bucket[tt * NNODES + base + t] : -1;
    __syncthreads();

    const int wave = t >> 6, lane = t & 63, lo = lane & 31, hi = lane >> 5;
    const int rt = wave >> 2;              // row-tile (32 nodes) this wave owns
    const int d  = (wave & 3) * 32 + lo;   // output column this wave owns
    const int rw = rt * 32 + lo;

    // stage X once (gathered h rows, split fp16, zero-fill inactive)
    for (int q = t; q < 64 * 32; q += 512) {
        int r = q >> 5, c4 = q & 31;
        float4 v = make_float4(0.f, 0.f, 0.f, 0.f);
        int node = bl[r];
        if (node >= 0) v = *(const float4*)(hT + (size_t)node * 128 + c4 * 4);
        half4 hh, ll;
        hh[0] = hi_(v.x); ll[0] = lo_(v.x);
        hh[1] = hi_(v.y); ll[1] = lo_(v.y);
        hh[2] = hi_(v.z); ll[2] = lo_(v.z);
        hh[3] = hi_(v.w); ll[3] = lo_(v.w);
        *(half4*)(Xh + r * PX + c4 * 4) = hh;
        *(half4*)(Xl + r * PX + c4 * 4) = ll;
    }

    float hacc[16];
    #pragma unroll
    for (int reg = 0; reg < 16; ++reg) hacc[reg] = 0.0f;

    #pragma unroll 1
    for (int v = 0; v < 2; ++v) {
        const float* msrc = v ? m_uni : m_non;
        __syncthreads();   // prev-variant Ms readers done (v=0: X stage commit)
        for (int q = t; q < 64 * 32; q += 512) {
            int r = q >> 5, c4 = q & 31;
            float4 mv = make_float4(0.f, 0.f, 0.f, 0.f);
            int node = bl[r];
            if (node >= 0) mv = *(const float4*)(msrc + (size_t)node * 128 + c4 * 4);
            half4 hh, ll;
            hh[0] = hi_(mv.x); ll[0] = lo_(mv.x);
            hh[1] = hi_(mv.y); ll[1] = lo_(mv.y);
            hh[2] = hi_(mv.z); ll[2] = lo_(mv.z);
            hh[3] = hi_(mv.w); ll[3] = lo_(mv.w);
            *(half4*)(Mh + r * PX + c4 * 4) = hh;
            *(half4*)(Ml + r * PX + c4 * 4) = ll;
        }
        __syncthreads();

        const int vt = v * NTYPE + tt;
        const _Float16* pih = Wp + (size_t)(vt * 2 + 0) * 98304;
        const _Float16* phh = Wp + (size_t)(vt * 2 + 1) * 98304;
        const float* bi = bihp + (size_t)vt * 384;
        const float* bh = bhhp + (size_t)vt * 384;

        // ---- pass 1: gates r and z ----
        floatx16 ar = (floatx16)0.0f, az = (floatx16)0.0f;
        #pragma unroll 2
        for (int kk = 0; kk < 8; ++kk) {
            int koff = kk * 16 + hi * 8;
            const _Float16* ci = pih + (size_t)(kk * 2 + hi) * 6144;
            const _Float16* ch = phh + (size_t)(kk * 2 + hi) * 6144;
            half8 birh = *(const half8*)(ci + (size_t)(0 + d) * 8);
            half8 birl = *(const half8*)(ci + 3072 + (size_t)(0 + d) * 8);
            half8 bhrh = *(const half8*)(ch + (size_t)(0 + d) * 8);
            half8 bhrl = *(const half8*)(ch + 3072 + (size_t)(0 + d) * 8);
            half8 bizh = *(const half8*)(ci + (size_t)(128 + d) * 8);
            half8 bizl = *(const half8*)(ci + 3072 + (size_t)(128 + d) * 8);
            half8 bhzh = *(const half8*)(ch + (size_t)(128 + d) * 8);
            half8 bhzl = *(const half8*)(ch + 3072 + (size_t)(128 + d) * 8);
            half8 xh = *(const half8*)(Xh + rw * PX + koff);
            half8 xl = *(const half8*)(Xl + rw * PX + koff);
            half8 mh = *(const half8*)(Mh + rw * PX + koff);
            half8 ml = *(const half8*)(Ml + rw * PX + koff);
            ar = __builtin_amdgcn_mfma_f32_32x32x16_f16(xh, birh, ar, 0, 0, 0);
            ar = __builtin_amdgcn_mfma_f32_32x32x16_f16(xh, birl, ar, 0, 0, 0);
            ar = __builtin_amdgcn_mfma_f32_32x32x16_f16(xl, birh, ar, 0, 0, 0);
            ar = __builtin_amdgcn_mfma_f32_32x32x16_f16(mh, bhrh, ar, 0, 0, 0);
            ar = __builtin_amdgcn_mfma_f32_32x32x16_f16(mh, bhrl, ar, 0, 0, 0);
            ar = __builtin_amdgcn_mfma_f32_32x32x16_f16(ml, bhrh, ar, 0, 0, 0);
            az = __builtin_amdgcn_mfma_f32_32x32x16_f16(xh, bizh, az, 0, 0, 0);
            az = __builtin_amdgcn_mfma_f32_32x32x16_f16(xh, bizl, az, 0, 0, 0);
            az = __builtin_amdgcn_mfma_f32_32x32x16_f16(xl, bizh, az, 0, 0, 0);
            az = __builtin_amdgcn_mfma_f32_32x32x16_f16(mh, bhzh, az, 0, 0, 0);
            az = __builtin_amdgcn_mfma_f32_32x32x16_f16(mh, bhzl, az, 0, 0, 0);
            az = __builtin_amdgcn_mfma_f32_32x32x16_f16(ml, bhzh, az, 0, 0, 0);
        }

        float rr[16], zz[16];
        {
            float b_r = bi[d] + bh[d];
            float b_z = bi[128 + d] + bh[128 + d];
            #pragma unroll
            for (int reg = 0; reg < 16; ++reg) {
                rr[reg] = sig_(ar[reg] + b_r);
                zz[reg] = sig_(az[reg] + b_z);
            }
        }

        // ---- pass 2: gate n ----
        floatx16 ax = (floatx16)0.0f, ah = (floatx16)0.0f;
        #pragma unroll 2
        for (int kk = 0; kk < 8; ++kk) {
            int koff = kk * 16 + hi * 8;
            const _Float16* ci = pih + (size_t)(kk * 2 + hi) * 6144;
            const _Float16* ch = phh + (size_t)(kk * 2 + hi) * 6144;
            half8 binh = *(const half8*)(ci + (size_t)(256 + d) * 8);
            half8 binl = *(const half8*)(ci + 3072 + (size_t)(256 + d) * 8);
            half8 bhnh = *(const half8*)(ch + (size_t)(256 + d) * 8);
            half8 bhnl = *(const half8*)(ch + 3072 + (size_t)(256 + d) * 8);
            half8 xh = *(const half8*)(Xh + rw * PX + koff);
            half8 xl = *(const half8*)(Xl + rw * PX + koff);
            half8 mh = *(const half8*)(Mh + rw * PX + koff);
            half8 ml = *(const half8*)(Ml + rw * PX + koff);
            ax = __builtin_amdgcn_mfma_f32_32x32x16_f16(xh, binh, ax, 0, 0, 0);
            ax = __builtin_amdgcn_mfma_f32_32x32x16_f16(xh, binl, ax, 0, 0, 0);
            ax = __builtin_amdgcn_mfma_f32_32x32x16_f16(xl, binh, ax, 0, 0, 0);
            ah = __builtin_amdgcn_mfma_f32_32x32x16_f16(mh, bhnh, ah, 0, 0, 0);
            ah = __builtin_amdgcn_mfma_f32_32x32x16_f16(mh, bhnl, ah, 0, 0, 0);
            ah = __builtin_amdgcn_mfma_f32_32x32x16_f16(ml, bhnh, ah, 0, 0, 0);
        }

        // ---- combine ----
        {
            float b_in = bi[256 + d];
            float b_hn = bh[256 + d];
            #pragma unroll
            for (int reg = 0; reg < 16; ++reg) {
                int n = rt * 32 + drow_(reg, hi);
                int node = bl[n];
                float nv = tanhf(ax[reg] + b_in + rr[reg] * (ah[reg] + b_hn));
                float mv = (node >= 0) ? msrc[(size_t)node * 128 + d] : 0.0f;
                hacc[reg] += (1.0f - zz[reg]) * nv + zz[reg] * mv;
            }
        }
    }

    // scatter h_new (coalesced along d)
    #pragma unroll
    for (int reg = 0; reg < 16; ++reg) {
        int n = rt * 32 + drow_(reg, hi);
        int node = bl[n];
        if (node >= 0) hT[(size_t)node * 128 + d] = hacc[reg];
    }
}

// ---------------------------------------------------------------- launch
extern "C" void kernel_launch(void* const* d_in, const int* in_sizes, int n_in,
                              void* d_out, int out_size, void* d_ws, size_t ws_size,
                              hipStream_t stream) {
    const float* g    = (const float*)d_in[0];
    const float* h    = (const float*)d_in[1];
    const float* msgW = (const float*)d_in[2];
    const float* Wih  = (const float*)d_in[3];
    const float* Whh  = (const float*)d_in[4];
    const float* bih  = (const float*)d_in[5];
    const float* bhh  = (const float*)d_in[6];
    float* hT = (float*)d_out;

    char* ws = (char*)d_ws;
    float* m_non = (float*)ws;                                   // 8 MB
    float* m_uni = m_non + (size_t)NNODES * 128;                 // 8 MB
    int* counts  = (int*)(ws + 2 * (size_t)NNODES * 128 * 4);
    int* bucket  = counts + 8;                                   // [6][16384]
    _Float16* WpM = (_Float16*)(bucket + NTYPE * NNODES);        // 1,835,008 halves (3.67 MB)
    _Float16* WpG = WpM + (size_t)NBOND * NLAY * 16 * 2048;      // 2,359,296 halves (4.72 MB)
    int* nblk = (int*)(WpG + (size_t)2 * NTYPE * 2 * 16 * 6144);
    int* desc = nblk + 4;

    (void)hipMemsetAsync(counts, 0, 8 * sizeof(int), stream);
    setup_kernel<<<NNODES * 128 / 256, 256, 0, stream>>>(h, hT, counts, bucket);
    desc_kernel<<<1, 64, 0, stream>>>(counts, desc, nblk);
    pack_msg_kernel<<<(NBOND * NLAY * 16 * 128 + 255) / 256, 256, 0, stream>>>(msgW, WpM);
    pack_gru_kernel<<<(2 * NTYPE * 2 * 16 * 384 + 255) / 256, 256, 0, stream>>>(Wih, Whh, WpG);

    for (int pass = 0; pass < 3; ++pass) {
        (void)hipMemsetAsync(m_non, 0, (size_t)NNODES * 128 * 4, stream);
        mlp_agg_mfma<<<dim3(128, NBOND), 256, 0, stream>>>(hT, WpM, g, m_non, m_uni);
        gru_mfma<<<dim3(GRUBLK), 512, 0, stream>>>(hT, m_non, m_uni, counts, bucket,
                                                   desc, nblk, WpG, bih, bhh);
    }
}